// Round 9
// baseline (1297.193 us; speedup 1.0000x reference)
//
#include <hip/hip_runtime.h>

#define UV_END_ 15360
#define MODOUT_ 16896

typedef __attribute__((ext_vector_type(8))) short s8v;
typedef __attribute__((ext_vector_type(4))) short s4v;
typedef __attribute__((ext_vector_type(8))) __bf16 bf16x8;
typedef __attribute__((ext_vector_type(4))) float f4v;
typedef __attribute__((ext_vector_type(4))) int i4v;

// keepalive: prevents DCE of a 16B fragment (rule #17) at ~3 VALU cost
#define KEEPV(v16) do { i4v _k = __builtin_bit_cast(i4v, (v16)); \
  int _t = (_k.x ^ _k.y) ^ (_k.z ^ _k.w); asm volatile("" :: "v"(_t)); } while (0)

static __device__ __forceinline__ unsigned short f2bf(float f) {
  unsigned u = __float_as_uint(f);
  u += 0x7fffu + ((u >> 16) & 1u);
  return (unsigned short)(u >> 16);
}
static __device__ __forceinline__ float bf2f(unsigned short s) {
  return __uint_as_float(((unsigned)s) << 16);
}

// 512-dot with 8 independent accumulator chains (64-deep each, not 512-deep)
static __device__ __forceinline__ float dot512i(const float* __restrict__ W,
                                                const float* __restrict__ hs) {
  const f4v* wr = (const f4v*)W;
  float a0 = 0, a1 = 0, a2 = 0, a3 = 0, a4 = 0, a5 = 0, a6 = 0, a7 = 0;
  #pragma unroll 4
  for (int c = 0; c < 128; c += 2) {
    f4v w0 = wr[c], w1 = wr[c + 1];
    a0 += w0.x * hs[c * 4 + 0]; a1 += w0.y * hs[c * 4 + 1];
    a2 += w0.z * hs[c * 4 + 2]; a3 += w0.w * hs[c * 4 + 3];
    a4 += w1.x * hs[c * 4 + 4]; a5 += w1.y * hs[c * 4 + 5];
    a6 += w1.z * hs[c * 4 + 6]; a7 += w1.w * hs[c * 4 + 7];
  }
  return ((a0 + a1) + (a2 + a3)) + ((a4 + a5) + (a6 + a7));
}

// ---------------- fused modulation net: 512 threads, 1 output/thread ----------
__global__ __launch_bounds__(512) void k_modnet(
    const float* __restrict__ latent, const float* __restrict__ ln_g,
    const float* __restrict__ ln_b,
    const float* __restrict__ Wm_in, const float* __restrict__ bm_in,
    const float* __restrict__ Wr1, const float* __restrict__ br1,
    const float* __restrict__ Wr2, const float* __restrict__ br2,
    float* __restrict__ hout) {
  __shared__ float A[512], B_[512], C[512];
  __shared__ float red[18];
  int b = blockIdx.x, t = threadIdx.x;
  int wv = t >> 6, ln = t & 63;
  float a0 = latent[b * 512 + t];
  float s = a0, q = a0 * a0;
  #pragma unroll
  for (int off = 32; off > 0; off >>= 1) {
    s += __shfl_down(s, off);
    q += __shfl_down(q, off);
  }
  if (ln == 0) { red[wv] = s; red[8 + wv] = q; }
  __syncthreads();
  if (t == 0) {
    float ss = 0, qq = 0;
    #pragma unroll
    for (int i = 0; i < 8; ++i) { ss += red[i]; qq += red[8 + i]; }
    float mean = ss * (1.0f / 512.0f);
    float var = qq * (1.0f / 512.0f) - mean * mean;
    red[16] = mean;
    red[17] = rsqrtf(var + 1e-5f);
  }
  __syncthreads();
  float mean = red[16], rstd = red[17];
  A[t] = (a0 - mean) * rstd * ln_g[t] + ln_b[t];
  __syncthreads();

  float acc = bm_in[t] + dot512i(Wm_in + (size_t)t * 512, A);
  B_[t] = acc > 0.f ? acc : 0.01f * acc;
  __syncthreads();
  acc = br1[t] + dot512i(Wr1 + (size_t)t * 512, B_);
  C[t] = acc > 0.f ? acc : 0.01f * acc;
  __syncthreads();
  acc = B_[t] + br2[t] + dot512i(Wr2 + (size_t)t * 512, C);
  A[t] = acc > 0.f ? acc : 0.01f * acc;
  __syncthreads();
  acc = br1[512 + t] + dot512i(Wr1 + 512 * 512 + (size_t)t * 512, A);
  C[t] = acc > 0.f ? acc : 0.01f * acc;
  __syncthreads();
  acc = A[t] + br2[512 + t] + dot512i(Wr2 + 512 * 512 + (size_t)t * 512, C);
  hout[b * 512 + t] = acc > 0.f ? acc : 0.01f * acc;
}

__global__ void k_modout(const float* __restrict__ h, const float* __restrict__ Wm,
                         const float* __restrict__ bm, const float* __restrict__ Wlast,
                         float* __restrict__ modout, float* __restrict__ Wfin) {
  int t = threadIdx.x;
  int o = blockIdx.x * 8 + (t >> 5);
  int b = t & 31;
  const f4v* wr = (const f4v*)(Wm + (size_t)o * 512);
  const f4v* hr = (const f4v*)(h + b * 512);
  float a0 = bm[o], a1 = 0, a2 = 0, a3 = 0;
  #pragma unroll 4
  for (int c = 0; c < 128; c += 2) {
    f4v w0 = wr[c], v0 = hr[c], w1 = wr[c + 1], v1 = hr[c + 1];
    a0 += w0.x * v0.x + w0.y * v0.y;
    a1 += w0.z * v0.z + w0.w * v0.w;
    a2 += w1.x * v1.x + w1.y * v1.y;
    a3 += w1.z * v1.z + w1.w * v1.w;
  }
  float acc = (a0 + a1) + (a2 + a3);
  if (o < UV_END_) {
    modout[(size_t)b * MODOUT_ + o] = acc;
  } else {
    int r = o - UV_END_;
    int od = r >> 9, hh = r & 511;
    float s = 1.f / (1.f + __expf(-acc));
    Wfin[(b * 3 + od) * 512 + hh] = s * Wlast[od * 512 + hh];
  }
}

// Wmod[b][l][h][i] = (sigmoid(sum_r U[b,l,h,r]*V[b,l,i,r]) + 1) * Wh[l][h][i]  (bf16)
__global__ void k_wprep(const float* __restrict__ modout, const float* __restrict__ Wh,
                        unsigned short* __restrict__ Wmod) {
  __shared__ float Vs[2560];
  __shared__ float Us[320];
  int ht = blockIdx.x, l = blockIdx.y, b = blockIdx.z, t = threadIdx.x;
  const float* mo = modout + (size_t)b * MODOUT_ + l * 5120;
  for (int i = t; i < 2560; i += 256) Vs[i] = mo[2560 + i];
  for (int i = t; i < 320; i += 256) Us[i] = mo[ht * 320 + i];
  __syncthreads();
  int hl = t >> 2;
  int h = ht * 64 + hl;
  float u0 = Us[hl * 5], u1 = Us[hl * 5 + 1], u2 = Us[hl * 5 + 2],
        u3 = Us[hl * 5 + 3], u4 = Us[hl * 5 + 4];
  const float* whr = Wh + ((size_t)(l * 512 + h)) * 512;
  unsigned short* wmr = Wmod + (((size_t)(b * 3 + l)) * 512 + h) * 512;
  for (int c = 0; c < 16; ++c) {
    int i0 = (t & 3) * 128 + c * 8;
    s8v pk;
    #pragma unroll
    for (int j = 0; j < 8; ++j) {
      int i = i0 + j;
      float gg = u0 * Vs[i * 5] + u1 * Vs[i * 5 + 1] + u2 * Vs[i * 5 + 2]
               + u3 * Vs[i * 5 + 3] + u4 * Vs[i * 5 + 4];
      float sg = 1.f / (1.f + __expf(-gg));
      float m = (sg + 1.f) * whr[i];
      pk[j] = (short)f2bf(m);
    }
    *(s8v*)(wmr + i0) = pk;
  }
}

// ---------------- fused SIREN main (templated for ablation) ----------------
// VAR 0: full kernel. VAR 1: NOGLB — A-fragments loaded once before the K-loop
// (removes per-step global loads; results wrong, dataflow intact). VAR 3:
// NOMFMA — 1 of 16 MFMAs kept, other fragments kept alive via asm (removes
// matrix-pipe cost; loads/LDS unchanged). Probes write to out and are fully
// overwritten by the final VAR=0 full-grid dispatch.
template <int VAR>
__global__ __launch_bounds__(512, 4) void k_main_t(
    const float* __restrict__ x, const float* __restrict__ W0w,
    const float* __restrict__ b0, const unsigned short* __restrict__ Wmod,
    const float* __restrict__ bh, const float* __restrict__ Wfin,
    const float* __restrict__ blast, float* __restrict__ outp) {
  __shared__ unsigned short hlds[64 * 512];
  const int bid = blockIdx.x;
  const int xcd = bid & 7, idx = bid >> 3;
  const int b = xcd * 4 + (idx >> 6);
  const int tile = idx & 63;
  const int t = threadIdx.x;
  const int lane = t & 63, wv = t >> 6;
  const int n0 = tile * 64;

  // ---- layer 0: h = sin(30*(x @ W0^T + b0)) straight into LDS
  {
    int n = t >> 3;
    float x0 = x[((size_t)b * 4096 + n0 + n) * 2 + 0];
    float x1 = x[((size_t)b * 4096 + n0 + n) * 2 + 1];
    int swz = (n & 7) << 3;
    int cbase = (t & 7) * 64;
    for (int c = 0; c < 8; ++c) {
      int i0 = cbase + c * 8;
      s8v pk;
      #pragma unroll
      for (int j = 0; j < 8; ++j) {
        int i = i0 + j;
        float pre = x0 * W0w[i * 2] + x1 * W0w[i * 2 + 1] + b0[i];
        pk[j] = (short)f2bf(__sinf(30.0f * pre));
      }
      *(s8v*)&hlds[n * 512 + (i0 ^ swz)] = pk;
    }
  }
  __syncthreads();

  const int arow = lane & 15;
  const int kgrp = (lane >> 4) * 8;
  const int hbase = wv * 64;

  for (int l = 0; l < 3; ++l) {
    const unsigned short* wp = Wmod + (((size_t)(b * 3 + l)) << 18)
                             + (size_t)(hbase + arow) * 512 + kgrp;
    f4v acc[4][4];
    #pragma unroll
    for (int fi = 0; fi < 4; ++fi)
      #pragma unroll
      for (int fj = 0; fj < 4; ++fj) { f4v z = {0.f, 0.f, 0.f, 0.f}; acc[fi][fj] = z; }

    s8v abuf[2][4];
    #pragma unroll
    for (int fi = 0; fi < 4; ++fi) abuf[0][fi] = *(const s8v*)(wp + fi * 16 * 512);

    // fully-unrolled, 1-deep-prefetch pipelined K-loop (compiler free to hoist)
    #pragma unroll
    for (int ks = 0; ks < 16; ++ks) {
      if (VAR != 1) {
        if (ks < 15) {
          #pragma unroll
          for (int fi = 0; fi < 4; ++fi)
            abuf[(ks + 1) & 1][fi] = *(const s8v*)(wp + fi * 16 * 512 + (ks + 1) * 32);
        }
      }
      const int cur = (VAR == 1) ? 0 : (ks & 1);
      int icol = ks * 32 + kgrp;
      bf16x8 bv[4];
      #pragma unroll
      for (int fj = 0; fj < 4; ++fj) {
        int n = fj * 16 + arow;
        bv[fj] = __builtin_bit_cast(bf16x8,
                   *(const s8v*)&hlds[n * 512 + (icol ^ ((n & 7) << 3))]);
      }
      __builtin_amdgcn_s_setprio(1);
      if (VAR == 3) {
        bf16x8 av0 = __builtin_bit_cast(bf16x8, abuf[cur][0]);
        acc[0][0] = __builtin_amdgcn_mfma_f32_16x16x32_bf16(av0, bv[0], acc[0][0], 0, 0, 0);
        KEEPV(abuf[cur][1]); KEEPV(abuf[cur][2]); KEEPV(abuf[cur][3]);
        KEEPV(bv[1]); KEEPV(bv[2]); KEEPV(bv[3]);
      } else {
        #pragma unroll
        for (int fi = 0; fi < 4; ++fi) {
          bf16x8 av = __builtin_bit_cast(bf16x8, abuf[cur][fi]);
          #pragma unroll
          for (int fj = 0; fj < 4; ++fj)
            acc[fi][fj] = __builtin_amdgcn_mfma_f32_16x16x32_bf16(av, bv[fj], acc[fi][fj], 0, 0, 0);
        }
      }
      __builtin_amdgcn_s_setprio(0);
    }
    __syncthreads();  // all waves done READING hlds before overwrite

    // epilogue: h_new[n][hh] = sin(30*(D[hh,n] + bh[hh])), in place
    const float* bhp = bh + l * 512;
    #pragma unroll
    for (int fi = 0; fi < 4; ++fi) {
      int hh = hbase + fi * 16 + (lane >> 4) * 4;
      float bv0 = bhp[hh], bv1 = bhp[hh + 1], bv2 = bhp[hh + 2], bv3 = bhp[hh + 3];
      #pragma unroll
      for (int fj = 0; fj < 4; ++fj) {
        int n = fj * 16 + arow;
        f4v a = acc[fi][fj];
        s4v pk;
        pk[0] = (short)f2bf(__sinf(30.f * (a.x + bv0)));
        pk[1] = (short)f2bf(__sinf(30.f * (a.y + bv1)));
        pk[2] = (short)f2bf(__sinf(30.f * (a.z + bv2)));
        pk[3] = (short)f2bf(__sinf(30.f * (a.w + bv3)));
        *(s4v*)&hlds[n * 512 + (hh ^ ((n & 7) << 3))] = pk;
      }
    }
    __syncthreads();
  }

  // ---- final projection: out[n][o] = h[n][:] . Wfin[b][o][:] + blast[o] + 0.5
  if (t < 192) {
    int n = t / 3, o = t - n * 3;
    const f4v* wf = (const f4v*)(Wfin + ((size_t)(b * 3 + o)) * 512);
    int swz = (n & 7) << 3;
    float acc = 0.f;
    #pragma unroll 4
    for (int c = 0; c < 64; ++c) {
      int i0 = c * 8;
      s8v hv = *(const s8v*)&hlds[n * 512 + (i0 ^ swz)];
      f4v w0 = wf[c * 2], w1 = wf[c * 2 + 1];
      acc += bf2f((unsigned short)hv[0]) * w0.x + bf2f((unsigned short)hv[1]) * w0.y
           + bf2f((unsigned short)hv[2]) * w0.z + bf2f((unsigned short)hv[3]) * w0.w
           + bf2f((unsigned short)hv[4]) * w1.x + bf2f((unsigned short)hv[5]) * w1.y
           + bf2f((unsigned short)hv[6]) * w1.z + bf2f((unsigned short)hv[7]) * w1.w;
    }
    outp[((size_t)b * 4096 + n0 + n) * 3 + o] = acc + blast[o] + 0.5f;
  }
}

extern "C" void kernel_launch(void* const* d_in, const int* in_sizes, int n_in,
                              void* d_out, int out_size, void* d_ws, size_t ws_size,
                              hipStream_t stream) {
  const float* x      = (const float*)d_in[0];
  const float* latent = (const float*)d_in[1];
  const float* W0w    = (const float*)d_in[2];
  const float* b0     = (const float*)d_in[3];
  const float* Wh     = (const float*)d_in[4];
  const float* bh     = (const float*)d_in[5];
  const float* Wlast  = (const float*)d_in[6];
  const float* blast  = (const float*)d_in[7];
  const float* ln_g   = (const float*)d_in[8];
  const float* ln_b   = (const float*)d_in[9];
  const float* Wm_in  = (const float*)d_in[10];
  const float* bm_in  = (const float*)d_in[11];
  const float* Wr1    = (const float*)d_in[12];
  const float* br1    = (const float*)d_in[13];
  const float* Wr2    = (const float*)d_in[14];
  const float* br2    = (const float*)d_in[15];
  const float* Wm_out = (const float*)d_in[16];
  const float* bm_out = (const float*)d_in[17];
  float* out = (float*)d_out;

  // workspace layout (all 16B-aligned)
  float* h1     = (float*)d_ws;                  // 32*512
  float* modout = h1 + 32 * 512;                 // 32*16896
  float* Wfin   = modout + (size_t)32 * MODOUT_; // 32*3*512
  unsigned short* Wmod = (unsigned short*)(Wfin + 32 * 3 * 512); // 48MB bf16

  k_modnet<<<32, 512, 0, stream>>>(latent, ln_g, ln_b, Wm_in, bm_in,
                                   Wr1, br1, Wr2, br2, h1);
  k_modout<<<2112, 256, 0, stream>>>(h1, Wm_out, bm_out, Wlast, modout, Wfin);
  k_wprep<<<dim3(8, 3, 32), 256, 0, stream>>>(modout, Wh, Wmod);

  // ---- ablation probes (grid 512 = 2 blocks/CU, write to out, overwritten
  // by the real dispatch below; rocprof reports each dispatch separately)
  k_main_t<0><<<512, 512, 0, stream>>>(x, W0w, b0, Wmod, bh, Wfin, blast, out);
  k_main_t<1><<<512, 512, 0, stream>>>(x, W0w, b0, Wmod, bh, Wfin, blast, out);
  k_main_t<3><<<512, 512, 0, stream>>>(x, W0w, b0, Wmod, bh, Wfin, blast, out);

  // ---- real dispatch (covers every (b, tile); overwrites probe output)
  k_main_t<0><<<2048, 512, 0, stream>>>(x, W0w, b0, Wmod, bh, Wfin, blast, out);
}

// Round 14
// 758.369 us; speedup vs baseline: 1.7105x; 1.7105x over previous
//
#include <hip/hip_runtime.h>

#define UV_END_ 15360
#define MODOUT_ 16896

typedef __attribute__((ext_vector_type(8))) short s8v;
typedef __attribute__((ext_vector_type(4))) short s4v;
typedef __attribute__((ext_vector_type(8))) __bf16 bf16x8;
typedef __attribute__((ext_vector_type(4))) float f4v;

static __device__ __forceinline__ unsigned short f2bf(float f) {
  unsigned u = __float_as_uint(f);
  u += 0x7fffu + ((u >> 16) & 1u);
  return (unsigned short)(u >> 16);
}
static __device__ __forceinline__ float bf2f(unsigned short s) {
  return __uint_as_float(((unsigned)s) << 16);
}

// 512-dot with 8 independent accumulator chains
static __device__ __forceinline__ float dot512i(const float* __restrict__ W,
                                                const float* __restrict__ hs) {
  const f4v* wr = (const f4v*)W;
  float a0 = 0, a1 = 0, a2 = 0, a3 = 0, a4 = 0, a5 = 0, a6 = 0, a7 = 0;
  #pragma unroll 4
  for (int c = 0; c < 128; c += 2) {
    f4v w0 = wr[c], w1 = wr[c + 1];
    a0 += w0.x * hs[c * 4 + 0]; a1 += w0.y * hs[c * 4 + 1];
    a2 += w0.z * hs[c * 4 + 2]; a3 += w0.w * hs[c * 4 + 3];
    a4 += w1.x * hs[c * 4 + 4]; a5 += w1.y * hs[c * 4 + 5];
    a6 += w1.z * hs[c * 4 + 6]; a7 += w1.w * hs[c * 4 + 7];
  }
  return ((a0 + a1) + (a2 + a3)) + ((a4 + a5) + (a6 + a7));
}

// ---------------- fused modulation net: 512 threads, 1 output/thread ----------
__global__ __launch_bounds__(512) void k_modnet(
    const float* __restrict__ latent, const float* __restrict__ ln_g,
    const float* __restrict__ ln_b,
    const float* __restrict__ Wm_in, const float* __restrict__ bm_in,
    const float* __restrict__ Wr1, const float* __restrict__ br1,
    const float* __restrict__ Wr2, const float* __restrict__ br2,
    float* __restrict__ hout) {
  __shared__ float A[512], B_[512], C[512];
  __shared__ float red[18];
  int b = blockIdx.x, t = threadIdx.x;
  int wv = t >> 6, ln = t & 63;
  float a0 = latent[b * 512 + t];
  float s = a0, q = a0 * a0;
  #pragma unroll
  for (int off = 32; off > 0; off >>= 1) {
    s += __shfl_down(s, off);
    q += __shfl_down(q, off);
  }
  if (ln == 0) { red[wv] = s; red[8 + wv] = q; }
  __syncthreads();
  if (t == 0) {
    float ss = 0, qq = 0;
    #pragma unroll
    for (int i = 0; i < 8; ++i) { ss += red[i]; qq += red[8 + i]; }
    float mean = ss * (1.0f / 512.0f);
    float var = qq * (1.0f / 512.0f) - mean * mean;
    red[16] = mean;
    red[17] = rsqrtf(var + 1e-5f);
  }
  __syncthreads();
  float mean = red[16], rstd = red[17];
  A[t] = (a0 - mean) * rstd * ln_g[t] + ln_b[t];
  __syncthreads();

  float acc = bm_in[t] + dot512i(Wm_in + (size_t)t * 512, A);
  B_[t] = acc > 0.f ? acc : 0.01f * acc;
  __syncthreads();
  acc = br1[t] + dot512i(Wr1 + (size_t)t * 512, B_);
  C[t] = acc > 0.f ? acc : 0.01f * acc;
  __syncthreads();
  acc = B_[t] + br2[t] + dot512i(Wr2 + (size_t)t * 512, C);
  A[t] = acc > 0.f ? acc : 0.01f * acc;
  __syncthreads();
  acc = br1[512 + t] + dot512i(Wr1 + 512 * 512 + (size_t)t * 512, A);
  C[t] = acc > 0.f ? acc : 0.01f * acc;
  __syncthreads();
  acc = A[t] + br2[512 + t] + dot512i(Wr2 + 512 * 512 + (size_t)t * 512, C);
  hout[b * 512 + t] = acc > 0.f ? acc : 0.01f * acc;
}

__global__ void k_modout(const float* __restrict__ h, const float* __restrict__ Wm,
                         const float* __restrict__ bm, const float* __restrict__ Wlast,
                         float* __restrict__ modout, float* __restrict__ Wfin) {
  int t = threadIdx.x;
  int o = blockIdx.x * 8 + (t >> 5);
  int b = t & 31;
  const f4v* wr = (const f4v*)(Wm + (size_t)o * 512);
  const f4v* hr = (const f4v*)(h + b * 512);
  float a0 = bm[o], a1 = 0, a2 = 0, a3 = 0;
  #pragma unroll 4
  for (int c = 0; c < 128; c += 2) {
    f4v w0 = wr[c], v0 = hr[c], w1 = wr[c + 1], v1 = hr[c + 1];
    a0 += w0.x * v0.x + w0.y * v0.y;
    a1 += w0.z * v0.z + w0.w * v0.w;
    a2 += w1.x * v1.x + w1.y * v1.y;
    a3 += w1.z * v1.z + w1.w * v1.w;
  }
  float acc = (a0 + a1) + (a2 + a3);
  if (o < UV_END_) {
    modout[(size_t)b * MODOUT_ + o] = acc;
  } else {
    int r = o - UV_END_;
    int od = r >> 9, hh = r & 511;
    float s = 1.f / (1.f + __expf(-acc));
    Wfin[(b * 3 + od) * 512 + hh] = s * Wlast[od * 512 + hh];
  }
}

// Wmod packed in MFMA-fragment-linear layout:
//   chunk(g, ks, lane) = W[g*16 + (lane&15)][ks*32 + ((lane>>4)&3)*8 .. +8)
//   stored at Wmod + (b,l)*2^18 + ((g*16 + ks)*64 + lane)*8 shorts
// so every A-load in k_main is ONE coalesced 1KB wave-instruction.
__global__ void k_wprep(const float* __restrict__ modout, const float* __restrict__ Wh,
                        unsigned short* __restrict__ Wmod) {
  __shared__ float Vs[2560];
  __shared__ float Us[320];
  int ht = blockIdx.x, l = blockIdx.y, b = blockIdx.z, t = threadIdx.x;
  const float* mo = modout + (size_t)b * MODOUT_ + l * 5120;
  for (int i = t; i < 2560; i += 256) Vs[i] = mo[2560 + i];
  for (int i = t; i < 320; i += 256) Us[i] = mo[ht * 320 + i];
  __syncthreads();
  int w = t >> 6, lane = t & 63;
  int arow = lane & 15, kq = (lane >> 4) & 3;
  int hl = w * 16 + arow;            // local h row in [0,64)
  int h = ht * 64 + hl;
  int g = ht * 4 + w;                // global 16-row group, 0..31
  float u0 = Us[hl * 5], u1 = Us[hl * 5 + 1], u2 = Us[hl * 5 + 2],
        u3 = Us[hl * 5 + 3], u4 = Us[hl * 5 + 4];
  const float* whr = Wh + ((size_t)(l * 512 + h)) * 512;
  unsigned short* base = Wmod + (((size_t)(b * 3 + l)) << 18);
  for (int ks = 0; ks < 16; ++ks) {
    int i0 = ks * 32 + kq * 8;
    s8v pk;
    #pragma unroll
    for (int j = 0; j < 8; ++j) {
      int i = i0 + j;
      float gg = u0 * Vs[i * 5] + u1 * Vs[i * 5 + 1] + u2 * Vs[i * 5 + 2]
               + u3 * Vs[i * 5 + 3] + u4 * Vs[i * 5 + 4];
      float sg = 1.f / (1.f + __expf(-gg));
      float m = (sg + 1.f) * whr[i];
      pk[j] = (short)f2bf(m);
    }
    // wave writes contiguous 1KB: ((g*16+ks)*64 + lane) * 8 shorts
    *(s8v*)(base + (((size_t)(g * 16 + ks)) << 9) + lane * 8) = pk;
  }
}

// ---------------- fused SIREN main ----------------
// 512 threads / 8 waves; wave wv owns hh in [wv*64, wv*64+64).
// h tile [64][512] bf16 in LDS, XOR-swizzled: slot(n,i) = n*512 + (i ^ ((n&7)<<3)).
// A-operand from fragment-packed Wmod: one coalesced 1KB load per (fi,ks).
__global__ __launch_bounds__(512, 4) void k_main(
    const float* __restrict__ x, const float* __restrict__ W0w,
    const float* __restrict__ b0, const unsigned short* __restrict__ Wmod,
    const float* __restrict__ bh, const float* __restrict__ Wfin,
    const float* __restrict__ blast, float* __restrict__ outp) {
  __shared__ unsigned short hlds[64 * 512];
  const int bid = blockIdx.x;
  const int xcd = bid & 7, idx = bid >> 3;       // 2048 = 8 * 256, bijective
  const int b = xcd * 4 + (idx >> 6);
  const int tile = idx & 63;
  const int t = threadIdx.x;
  const int lane = t & 63, wv = t >> 6;
  const int n0 = tile * 64;

  // ---- layer 0: h = sin(30*(x @ W0^T + b0)) straight into LDS
  {
    int n = t >> 3;
    float x0 = x[((size_t)b * 4096 + n0 + n) * 2 + 0];
    float x1 = x[((size_t)b * 4096 + n0 + n) * 2 + 1];
    int swz = (n & 7) << 3;
    int cbase = (t & 7) * 64;
    for (int c = 0; c < 8; ++c) {
      int i0 = cbase + c * 8;
      s8v pk;
      #pragma unroll
      for (int j = 0; j < 8; ++j) {
        int i = i0 + j;
        float pre = x0 * W0w[i * 2] + x1 * W0w[i * 2 + 1] + b0[i];
        pk[j] = (short)f2bf(__sinf(30.0f * pre));
      }
      *(s8v*)&hlds[n * 512 + (i0 ^ swz)] = pk;
    }
  }
  __syncthreads();

  const int arow = lane & 15;
  const int kgrp = (lane >> 4) * 8;
  const int hbase = wv * 64;

  for (int l = 0; l < 3; ++l) {
    // fragment-packed base for this wave: + hbase*512 + lane*8 (shorts)
    const unsigned short* wpf = Wmod + (((size_t)(b * 3 + l)) << 18)
                              + ((size_t)hbase << 9) + lane * 8;
    f4v acc[4][4];
    #pragma unroll
    for (int fi = 0; fi < 4; ++fi)
      #pragma unroll
      for (int fj = 0; fj < 4; ++fj) { f4v z = {0.f, 0.f, 0.f, 0.f}; acc[fi][fj] = z; }

    s8v abuf[2][4];
    #pragma unroll
    for (int fi = 0; fi < 4; ++fi)
      abuf[0][fi] = *(const s8v*)(wpf + fi * 8192);

    #pragma unroll
    for (int ks = 0; ks < 16; ++ks) {
      if (ks < 15) {
        #pragma unroll
        for (int fi = 0; fi < 4; ++fi)
          abuf[(ks + 1) & 1][fi] = *(const s8v*)(wpf + fi * 8192 + (ks + 1) * 512);
      }
      const int cur = ks & 1;
      int icol = ks * 32 + kgrp;
      bf16x8 bv[4];
      #pragma unroll
      for (int fj = 0; fj < 4; ++fj) {
        int n = fj * 16 + arow;
        bv[fj] = __builtin_bit_cast(bf16x8,
                   *(const s8v*)&hlds[n * 512 + (icol ^ ((n & 7) << 3))]);
      }
      __builtin_amdgcn_s_setprio(1);
      #pragma unroll
      for (int fi = 0; fi < 4; ++fi) {
        bf16x8 av = __builtin_bit_cast(bf16x8, abuf[cur][fi]);
        #pragma unroll
        for (int fj = 0; fj < 4; ++fj)
          acc[fi][fj] = __builtin_amdgcn_mfma_f32_16x16x32_bf16(av, bv[fj], acc[fi][fj], 0, 0, 0);
      }
      __builtin_amdgcn_s_setprio(0);
    }
    __syncthreads();  // all waves done READING hlds before overwrite

    // epilogue: h_new[n][hh] = sin(30*(D[hh,n] + bh[hh])), in place
    const float* bhp = bh + l * 512;
    #pragma unroll
    for (int fi = 0; fi < 4; ++fi) {
      int hh = hbase + fi * 16 + (lane >> 4) * 4;
      float bv0 = bhp[hh], bv1 = bhp[hh + 1], bv2 = bhp[hh + 2], bv3 = bhp[hh + 3];
      #pragma unroll
      for (int fj = 0; fj < 4; ++fj) {
        int n = fj * 16 + arow;
        f4v a = acc[fi][fj];
        s4v pk;
        pk[0] = (short)f2bf(__sinf(30.f * (a.x + bv0)));
        pk[1] = (short)f2bf(__sinf(30.f * (a.y + bv1)));
        pk[2] = (short)f2bf(__sinf(30.f * (a.z + bv2)));
        pk[3] = (short)f2bf(__sinf(30.f * (a.w + bv3)));
        *(s4v*)&hlds[n * 512 + (hh ^ ((n & 7) << 3))] = pk;
      }
    }
    __syncthreads();
  }

  // ---- final projection: out[n][o] = h[n][:] . Wfin[b][o][:] + blast[o] + 0.5
  if (t < 192) {
    int n = t / 3, o = t - n * 3;
    const f4v* wf = (const f4v*)(Wfin + ((size_t)(b * 3 + o)) * 512);
    int swz = (n & 7) << 3;
    float acc = 0.f;
    #pragma unroll 4
    for (int c = 0; c < 64; ++c) {
      int i0 = c * 8;
      s8v hv = *(const s8v*)&hlds[n * 512 + (i0 ^ swz)];
      f4v w0 = wf[c * 2], w1 = wf[c * 2 + 1];
      acc += bf2f((unsigned short)hv[0]) * w0.x + bf2f((unsigned short)hv[1]) * w0.y
           + bf2f((unsigned short)hv[2]) * w0.z + bf2f((unsigned short)hv[3]) * w0.w
           + bf2f((unsigned short)hv[4]) * w1.x + bf2f((unsigned short)hv[5]) * w1.y
           + bf2f((unsigned short)hv[6]) * w1.z + bf2f((unsigned short)hv[7]) * w1.w;
    }
    outp[((size_t)b * 4096 + n0 + n) * 3 + o] = acc + blast[o] + 0.5f;
  }
}

extern "C" void kernel_launch(void* const* d_in, const int* in_sizes, int n_in,
                              void* d_out, int out_size, void* d_ws, size_t ws_size,
                              hipStream_t stream) {
  const float* x      = (const float*)d_in[0];
  const float* latent = (const float*)d_in[1];
  const float* W0w    = (const float*)d_in[2];
  const float* b0     = (const float*)d_in[3];
  const float* Wh     = (const float*)d_in[4];
  const float* bh     = (const float*)d_in[5];
  const float* Wlast  = (const float*)d_in[6];
  const float* blast  = (const float*)d_in[7];
  const float* ln_g   = (const float*)d_in[8];
  const float* ln_b   = (const float*)d_in[9];
  const float* Wm_in  = (const float*)d_in[10];
  const float* bm_in  = (const float*)d_in[11];
  const float* Wr1    = (const float*)d_in[12];
  const float* br1    = (const float*)d_in[13];
  const float* Wr2    = (const float*)d_in[14];
  const float* br2    = (const float*)d_in[15];
  const float* Wm_out = (const float*)d_in[16];
  const float* bm_out = (const float*)d_in[17];
  float* out = (float*)d_out;

  // workspace layout (all 16B-aligned)
  float* h1     = (float*)d_ws;                  // 32*512
  float* modout = h1 + 32 * 512;                 // 32*16896
  float* Wfin   = modout + (size_t)32 * MODOUT_; // 32*3*512
  unsigned short* Wmod = (unsigned short*)(Wfin + 32 * 3 * 512); // 48MB bf16

  k_modnet<<<32, 512, 0, stream>>>(latent, ln_g, ln_b, Wm_in, bm_in,
                                   Wr1, br1, Wr2, br2, h1);
  k_modout<<<2112, 256, 0, stream>>>(h1, Wm_out, bm_out, Wlast, modout, Wfin);
  k_wprep<<<dim3(8, 3, 32), 256, 0, stream>>>(modout, Wh, Wmod);
  k_main<<<2048, 512, 0, stream>>>(x, W0w, b0, Wmod, bh, Wfin, blast, out);
}

// Round 15
// 753.578 us; speedup vs baseline: 1.7214x; 1.0064x over previous
//
#include <hip/hip_runtime.h>

#define UV_END_ 15360
#define MODOUT_ 16896

typedef __attribute__((ext_vector_type(8))) short s8v;
typedef __attribute__((ext_vector_type(4))) short s4v;
typedef __attribute__((ext_vector_type(8))) __bf16 bf16x8;
typedef __attribute__((ext_vector_type(4))) float f4v;

static __device__ __forceinline__ unsigned short f2bf(float f) {
  unsigned u = __float_as_uint(f);
  u += 0x7fffu + ((u >> 16) & 1u);
  return (unsigned short)(u >> 16);
}
static __device__ __forceinline__ float bf2f(unsigned short s) {
  return __uint_as_float(((unsigned)s) << 16);
}

// ---------------- fused modulation net ----------------
// Wave-per-output shuffle-GEMV: for output o, lane ln reads W[o][ln*8..+8)
// (wave reads the 2KB row in 2 coalesced insts), 8 FMA, 64-lane butterfly.
// Replaces the lane-per-row layout whose 2KB-stride reads serialized the
// request path (same pathology fixed in k_main by fragment packing).
static __device__ __forceinline__ void gemv512(
    const float* __restrict__ W, const float* __restrict__ bias,
    const float* __restrict__ IN, const float* __restrict__ RES,
    float* __restrict__ OUT, int wv, int ln) {
  float iv0 = IN[ln * 8 + 0], iv1 = IN[ln * 8 + 1], iv2 = IN[ln * 8 + 2],
        iv3 = IN[ln * 8 + 3], iv4 = IN[ln * 8 + 4], iv5 = IN[ln * 8 + 5],
        iv6 = IN[ln * 8 + 6], iv7 = IN[ln * 8 + 7];
  #pragma unroll 2
  for (int oo = 0; oo < 64; ++oo) {
    int o = wv * 64 + oo;
    const f4v* wr = (const f4v*)(W + (size_t)o * 512 + ln * 8);
    f4v w0 = wr[0], w1 = wr[1];
    float p = w0.x * iv0 + w0.y * iv1 + w0.z * iv2 + w0.w * iv3
            + w1.x * iv4 + w1.y * iv5 + w1.z * iv6 + w1.w * iv7;
    #pragma unroll
    for (int off = 1; off < 64; off <<= 1) p += __shfl_xor(p, off);
    if (ln == 0) {
      float acc = bias[o] + p + (RES ? RES[o] : 0.f);
      OUT[o] = acc > 0.f ? acc : 0.01f * acc;
    }
  }
}

__global__ __launch_bounds__(512) void k_modnet(
    const float* __restrict__ latent, const float* __restrict__ ln_g,
    const float* __restrict__ ln_b,
    const float* __restrict__ Wm_in, const float* __restrict__ bm_in,
    const float* __restrict__ Wr1, const float* __restrict__ br1,
    const float* __restrict__ Wr2, const float* __restrict__ br2,
    float* __restrict__ houtT) {       // houtT[512][32] transposed
  __shared__ float A[512], B_[512], C[512];
  __shared__ float red[18];
  int b = blockIdx.x, t = threadIdx.x;
  int wv = t >> 6, ln = t & 63;
  float a0 = latent[b * 512 + t];
  float s = a0, q = a0 * a0;
  #pragma unroll
  for (int off = 32; off > 0; off >>= 1) {
    s += __shfl_down(s, off);
    q += __shfl_down(q, off);
  }
  if (ln == 0) { red[wv] = s; red[8 + wv] = q; }
  __syncthreads();
  if (t == 0) {
    float ss = 0, qq = 0;
    #pragma unroll
    for (int i = 0; i < 8; ++i) { ss += red[i]; qq += red[8 + i]; }
    float mean = ss * (1.0f / 512.0f);
    float var = qq * (1.0f / 512.0f) - mean * mean;
    red[16] = mean;
    red[17] = rsqrtf(var + 1e-5f);
  }
  __syncthreads();
  float mean = red[16], rstd = red[17];
  A[t] = (a0 - mean) * rstd * ln_g[t] + ln_b[t];
  __syncthreads();

  gemv512(Wm_in, bm_in, A, nullptr, B_, wv, ln);                 // h
  __syncthreads();
  gemv512(Wr1, br1, B_, nullptr, C, wv, ln);                     // t
  __syncthreads();
  gemv512(Wr2, br2, C, B_, A, wv, ln);                           // h = leaky(h+t2)
  __syncthreads();
  gemv512(Wr1 + 512 * 512, br1 + 512, A, nullptr, C, wv, ln);
  __syncthreads();
  gemv512(Wr2 + 512 * 512, br2 + 512, C, A, B_, wv, ln);
  __syncthreads();
  houtT[t * 32 + b] = B_[t];   // transposed store for modout coalescing
}

// out(b,o) = hT-column dot: hT reads are 1 cache line per wave-inst (broadcast
// across the two 32-lane o-groups), W reads wave-uniform per o-group.
__global__ void k_modout(const float* __restrict__ hT, const float* __restrict__ Wm,
                         const float* __restrict__ bm, const float* __restrict__ Wlast,
                         float* __restrict__ modout, float* __restrict__ Wfin) {
  int t = threadIdx.x;
  int o = blockIdx.x * 8 + (t >> 5);
  int b = t & 31;
  const f4v* wr = (const f4v*)(Wm + (size_t)o * 512);
  float a0 = bm[o], a1 = 0, a2 = 0, a3 = 0;
  #pragma unroll 4
  for (int c = 0; c < 128; ++c) {
    f4v w = wr[c];
    a0 += w.x * hT[(c * 4 + 0) * 32 + b];
    a1 += w.y * hT[(c * 4 + 1) * 32 + b];
    a2 += w.z * hT[(c * 4 + 2) * 32 + b];
    a3 += w.w * hT[(c * 4 + 3) * 32 + b];
  }
  float acc = (a0 + a1) + (a2 + a3);
  if (o < UV_END_) {
    modout[(size_t)b * MODOUT_ + o] = acc;
  } else {
    int r = o - UV_END_;
    int od = r >> 9, hh = r & 511;
    float s = 1.f / (1.f + __expf(-acc));
    Wfin[(b * 3 + od) * 512 + hh] = s * Wlast[od * 512 + hh];
  }
}

// Wmod packed in MFMA-fragment-linear layout:
//   chunk(g, ks, lane) = W[g*16 + (lane&15)][ks*32 + ((lane>>4)&3)*8 .. +8)
//   stored at Wmod + (b,l)*2^18 + ((g*16 + ks)*64 + lane)*8 shorts
__global__ void k_wprep(const float* __restrict__ modout, const float* __restrict__ Wh,
                        unsigned short* __restrict__ Wmod) {
  __shared__ float Vs[2560];
  __shared__ float Us[320];
  int ht = blockIdx.x, l = blockIdx.y, b = blockIdx.z, t = threadIdx.x;
  const float* mo = modout + (size_t)b * MODOUT_ + l * 5120;
  for (int i = t; i < 2560; i += 256) Vs[i] = mo[2560 + i];
  for (int i = t; i < 320; i += 256) Us[i] = mo[ht * 320 + i];
  __syncthreads();
  int w = t >> 6, lane = t & 63;
  int arow = lane & 15, kq = (lane >> 4) & 3;
  int hl = w * 16 + arow;
  int h = ht * 64 + hl;
  int g = ht * 4 + w;
  float u0 = Us[hl * 5], u1 = Us[hl * 5 + 1], u2 = Us[hl * 5 + 2],
        u3 = Us[hl * 5 + 3], u4 = Us[hl * 5 + 4];
  const float* whr = Wh + ((size_t)(l * 512 + h)) * 512;
  unsigned short* base = Wmod + (((size_t)(b * 3 + l)) << 18);
  for (int ks = 0; ks < 16; ++ks) {
    int i0 = ks * 32 + kq * 8;
    s8v pk;
    #pragma unroll
    for (int j = 0; j < 8; ++j) {
      int i = i0 + j;
      float gg = u0 * Vs[i * 5] + u1 * Vs[i * 5 + 1] + u2 * Vs[i * 5 + 2]
               + u3 * Vs[i * 5 + 3] + u4 * Vs[i * 5 + 4];
      float sg = 1.f / (1.f + __expf(-gg));
      float m = (sg + 1.f) * whr[i];
      pk[j] = (short)f2bf(m);
    }
    *(s8v*)(base + (((size_t)(g * 16 + ks)) << 9) + lane * 8) = pk;
  }
}

// ---------------- fused SIREN main ----------------
// Single A-buffer per K-step (R14's manual [2][4] ping-pong + full unroll
// overflowed the 128-reg cap -> 141MB scratch; compiler pipelines the
// fully-unrolled loop itself).
__global__ __launch_bounds__(512, 4) void k_main(
    const float* __restrict__ x, const float* __restrict__ W0w,
    const float* __restrict__ b0, const unsigned short* __restrict__ Wmod,
    const float* __restrict__ bh, const float* __restrict__ Wfin,
    const float* __restrict__ blast, float* __restrict__ outp) {
  __shared__ unsigned short hlds[64 * 512];
  const int bid = blockIdx.x;
  const int xcd = bid & 7, idx = bid >> 3;       // 2048 = 8 * 256, bijective
  const int b = xcd * 4 + (idx >> 6);
  const int tile = idx & 63;
  const int t = threadIdx.x;
  const int lane = t & 63, wv = t >> 6;
  const int n0 = tile * 64;

  // ---- layer 0: h = sin(30*(x @ W0^T + b0)) straight into LDS
  {
    int n = t >> 3;
    float x0 = x[((size_t)b * 4096 + n0 + n) * 2 + 0];
    float x1 = x[((size_t)b * 4096 + n0 + n) * 2 + 1];
    int swz = (n & 7) << 3;
    int cbase = (t & 7) * 64;
    for (int c = 0; c < 8; ++c) {
      int i0 = cbase + c * 8;
      s8v pk;
      #pragma unroll
      for (int j = 0; j < 8; ++j) {
        int i = i0 + j;
        float pre = x0 * W0w[i * 2] + x1 * W0w[i * 2 + 1] + b0[i];
        pk[j] = (short)f2bf(__sinf(30.0f * pre));
      }
      *(s8v*)&hlds[n * 512 + (i0 ^ swz)] = pk;
    }
  }
  __syncthreads();

  const int arow = lane & 15;
  const int kgrp = (lane >> 4) * 8;
  const int hbase = wv * 64;

  for (int l = 0; l < 3; ++l) {
    const unsigned short* wpf = Wmod + (((size_t)(b * 3 + l)) << 18)
                              + ((size_t)hbase << 9) + lane * 8;
    f4v acc[4][4];
    #pragma unroll
    for (int fi = 0; fi < 4; ++fi)
      #pragma unroll
      for (int fj = 0; fj < 4; ++fj) { f4v z = {0.f, 0.f, 0.f, 0.f}; acc[fi][fj] = z; }

    #pragma unroll
    for (int ks = 0; ks < 16; ++ks) {
      s8v ab[4];
      #pragma unroll
      for (int fi = 0; fi < 4; ++fi)
        ab[fi] = *(const s8v*)(wpf + fi * 8192 + ks * 512);
      int icol = ks * 32 + kgrp;
      bf16x8 bv[4];
      #pragma unroll
      for (int fj = 0; fj < 4; ++fj) {
        int n = fj * 16 + arow;
        bv[fj] = __builtin_bit_cast(bf16x8,
                   *(const s8v*)&hlds[n * 512 + (icol ^ ((n & 7) << 3))]);
      }
      __builtin_amdgcn_s_setprio(1);
      #pragma unroll
      for (int fi = 0; fi < 4; ++fi) {
        bf16x8 av = __builtin_bit_cast(bf16x8, ab[fi]);
        #pragma unroll
        for (int fj = 0; fj < 4; ++fj)
          acc[fi][fj] = __builtin_amdgcn_mfma_f32_16x16x32_bf16(av, bv[fj], acc[fi][fj], 0, 0, 0);
      }
      __builtin_amdgcn_s_setprio(0);
    }
    __syncthreads();  // all waves done READING hlds before overwrite

    // epilogue: h_new[n][hh] = sin(30*(D[hh,n] + bh[hh])), in place
    const float* bhp = bh + l * 512;
    #pragma unroll
    for (int fi = 0; fi < 4; ++fi) {
      int hh = hbase + fi * 16 + (lane >> 4) * 4;
      float bv0 = bhp[hh], bv1 = bhp[hh + 1], bv2 = bhp[hh + 2], bv3 = bhp[hh + 3];
      #pragma unroll
      for (int fj = 0; fj < 4; ++fj) {
        int n = fj * 16 + arow;
        f4v a = acc[fi][fj];
        s4v pk;
        pk[0] = (short)f2bf(__sinf(30.f * (a.x + bv0)));
        pk[1] = (short)f2bf(__sinf(30.f * (a.y + bv1)));
        pk[2] = (short)f2bf(__sinf(30.f * (a.z + bv2)));
        pk[3] = (short)f2bf(__sinf(30.f * (a.w + bv3)));
        *(s4v*)&hlds[n * 512 + (hh ^ ((n & 7) << 3))] = pk;
      }
    }
    __syncthreads();
  }

  // ---- final projection: out[n][o] = h[n][:] . Wfin[b][o][:] + blast[o] + 0.5
  if (t < 192) {
    int n = t / 3, o = t - n * 3;
    const f4v* wf = (const f4v*)(Wfin + ((size_t)(b * 3 + o)) * 512);
    int swz = (n & 7) << 3;
    float acc = 0.f;
    #pragma unroll 4
    for (int c = 0; c < 64; ++c) {
      int i0 = c * 8;
      s8v hv = *(const s8v*)&hlds[n * 512 + (i0 ^ swz)];
      f4v w0 = wf[c * 2], w1 = wf[c * 2 + 1];
      acc += bf2f((unsigned short)hv[0]) * w0.x + bf2f((unsigned short)hv[1]) * w0.y
           + bf2f((unsigned short)hv[2]) * w0.z + bf2f((unsigned short)hv[3]) * w0.w
           + bf2f((unsigned short)hv[4]) * w1.x + bf2f((unsigned short)hv[5]) * w1.y
           + bf2f((unsigned short)hv[6]) * w1.z + bf2f((unsigned short)hv[7]) * w1.w;
    }
    outp[((size_t)b * 4096 + n0 + n) * 3 + o] = acc + blast[o] + 0.5f;
  }
}

extern "C" void kernel_launch(void* const* d_in, const int* in_sizes, int n_in,
                              void* d_out, int out_size, void* d_ws, size_t ws_size,
                              hipStream_t stream) {
  const float* x      = (const float*)d_in[0];
  const float* latent = (const float*)d_in[1];
  const float* W0w    = (const float*)d_in[2];
  const float* b0     = (const float*)d_in[3];
  const float* Wh     = (const float*)d_in[4];
  const float* bh     = (const float*)d_in[5];
  const float* Wlast  = (const float*)d_in[6];
  const float* blast  = (const float*)d_in[7];
  const float* ln_g   = (const float*)d_in[8];
  const float* ln_b   = (const float*)d_in[9];
  const float* Wm_in  = (const float*)d_in[10];
  const float* bm_in  = (const float*)d_in[11];
  const float* Wr1    = (const float*)d_in[12];
  const float* br1    = (const float*)d_in[13];
  const float* Wr2    = (const float*)d_in[14];
  const float* br2    = (const float*)d_in[15];
  const float* Wm_out = (const float*)d_in[16];
  const float* bm_out = (const float*)d_in[17];
  float* out = (float*)d_out;

  // workspace layout (all 16B-aligned)
  float* hT     = (float*)d_ws;                  // 512*32 (transposed h1)
  float* modout = hT + 32 * 512;                 // 32*16896
  float* Wfin   = modout + (size_t)32 * MODOUT_; // 32*3*512
  unsigned short* Wmod = (unsigned short*)(Wfin + 32 * 3 * 512); // 48MB bf16

  k_modnet<<<32, 512, 0, stream>>>(latent, ln_g, ln_b, Wm_in, bm_in,
                                   Wr1, br1, Wr2, br2, hT);
  k_modout<<<2112, 256, 0, stream>>>(hT, Wm_out, bm_out, Wlast, modout, Wfin);
  k_wprep<<<dim3(8, 3, 32), 256, 0, stream>>>(modout, Wh, Wmod);
  k_main<<<2048, 512, 0, stream>>>(x, W0w, b0, Wmod, bh, Wfin, blast, out);
}